// Round 2
// baseline (25462.186 us; speedup 1.0000x reference)
//
#include <hip/hip_runtime.h>

static constexpr int kB = 128, kS = 512, kH = 768;

typedef __attribute__((ext_vector_type(8))) short short8;
typedef __attribute__((ext_vector_type(4))) float f32x4;

__device__ __forceinline__ unsigned short f2bf(float x) {
  unsigned u = __float_as_uint(x);
  u += 0x7fffu + ((u >> 16) & 1u);   // RNE
  return (unsigned short)(u >> 16);
}
__device__ __forceinline__ float bf2f(unsigned short h) {
  return __uint_as_float(((unsigned)h) << 16);
}
__device__ __forceinline__ short8 pack_bf8(const float* __restrict__ p) {
  short8 r;
#pragma unroll
  for (int i = 0; i < 8; ++i) r[i] = (short)f2bf(p[i]);
  return r;
}
__device__ __forceinline__ float fsigm(float x) {
  return __builtin_amdgcn_rcpf(1.0f + __expf(-x));
}
__device__ __forceinline__ float ftanh(float x) {
  return 1.0f - 2.0f * __builtin_amdgcn_rcpf(1.0f + __expf(2.0f * x));
}

// ---------------- fp32 -> bf16 cast ----------------
__global__ __launch_bounds__(256) void cast_bf16_kernel(const float* __restrict__ src,
                                                        unsigned short* __restrict__ dst,
                                                        int n) {
  int i = (blockIdx.x * 256 + threadIdx.x) * 4;
  if (i < n) {
    float4 v = *(const float4*)(src + i);
    *(ushort4*)(dst + i) = make_ushort4(f2bf(v.x), f2bf(v.y), f2bf(v.z), f2bf(v.w));
  }
}

// ---------------- diagnostic canary: pre-fill ys ----------------
__global__ __launch_bounds__(256) void fill_kernel(float* __restrict__ p, int n) {
  int i = (blockIdx.x * 256 + threadIdx.x) * 4;
  if (i < n) *(float4*)(p + i) = make_float4(100.f, 100.f, 100.f, 100.f);
}

// ---------------- device-scope group barrier ----------------
__device__ __forceinline__ void group_barrier(unsigned* cnt, unsigned target) {
  __syncthreads();                                      // all waves' stores issued+drained
  __builtin_amdgcn_fence(__ATOMIC_RELEASE, "agent");    // L2 writeback -> visible cross-XCD
  if (threadIdx.x == 0) {
    __hip_atomic_fetch_add(cnt, 1u, __ATOMIC_RELAXED, __HIP_MEMORY_SCOPE_AGENT);
    while (__hip_atomic_load(cnt, __ATOMIC_RELAXED, __HIP_MEMORY_SCOPE_AGENT) < target)
      __builtin_amdgcn_s_sleep(2);
  }
  __syncthreads();
  __builtin_amdgcn_fence(__ATOMIC_ACQUIRE, "agent");    // invalidate stale L1/L2
}

// ---------------- the scan ----------------
// 192 blocks: g = bid&3 -> batch rows [g*32, +32); stripe = bid>>2 -> hidden cols [stripe*16, +16)
// wave w = gate w (f,i,o,c~) over 2 M-tiles; waves 0,1 additionally do the W_d GEMM
// for M-tile w. Weight B-frags (W, U, W_d stripes) live in VGPRs for the whole kernel.
// h/c exchanged through global bf16 ping-pong buffers; c master copy is fp32 in LDS.
__global__ __launch_bounds__(256, 1) void scan_kernel(
    const unsigned short* __restrict__ Xb, unsigned short* __restrict__ hbuf,
    unsigned short* __restrict__ cbuf, const float* __restrict__ Wall,
    const float* __restrict__ Wallb, const float* __restrict__ Uall,
    const float* __restrict__ Uallb, const float* __restrict__ Wd,
    const float* __restrict__ Wdb, const float* __restrict__ ts,
    const float* __restrict__ c0, float* __restrict__ ys, unsigned* bar) {
  __shared__ float lds_pre[4][32][16];
  __shared__ float lds_d[32][16];
  __shared__ float lds_cm[32][16];

  const int t = threadIdx.x;
  const int w = t >> 6, lane = t & 63, l15 = lane & 15, lhi = lane >> 4;
  const int g = blockIdx.x & 3, stripe = blockIdx.x >> 2;
  const int b0 = g * 32, j0 = stripe * 16;
  unsigned* cnt = bar + g * 16;  // 64B apart

  // step-invariant weights -> registers. B-frag: n=l15 (output col), k=lhi*8+j
  short8 wg[24], ug[24], wdv[24];
#pragma unroll
  for (int kk = 0; kk < 24; ++kk) {
    const float* wrow = Wall + (size_t)(w * kH + j0 + l15) * kH + kk * 32 + lhi * 8;
    const float* urow = Uall + (size_t)(w * kH + j0 + l15) * kH + kk * 32 + lhi * 8;
    const float* drow = Wd + (size_t)(j0 + l15) * kH + kk * 32 + lhi * 8;
    wg[kk] = pack_bf8(wrow);
    ug[kk] = pack_bf8(urow);
    wdv[kk] = pack_bf8(drow);
  }

  // elementwise mapping: 32 rows x 8 thread-cols x 2 elems
  const int erow = t >> 3, eq = t & 7;
  const int eb = b0 + erow, jc = j0 + eq * 2;
  {
    float2 v = *(const float2*)(c0 + (size_t)eb * kH + jc);
    lds_cm[erow][eq * 2 + 0] = v.x;
    lds_cm[erow][eq * 2 + 1] = v.y;
  }
  float bsum[4][2], bd[2];
#pragma unroll
  for (int gg = 0; gg < 4; ++gg)
#pragma unroll
    for (int u = 0; u < 2; ++u) bsum[gg][u] = Wallb[gg * kH + jc + u] + Uallb[gg * kH + jc + u];
#pragma unroll
  for (int u = 0; u < 2; ++u) bd[u] = Wdb[jc + u];

  int hoff[2], xoff[2];
#pragma unroll
  for (int mt = 0; mt < 2; ++mt) {
    hoff[mt] = (b0 + mt * 16 + l15) * kH + lhi * 8;
    xoff[mt] = (b0 + mt * 16 + l15) * kS * kH + lhi * 8;
  }
  const int coff = (b0 + (w & 1) * 16 + l15) * kH + lhi * 8;
  const bool do_c = (w < 2);

  const float* tsrow = ts + (size_t)eb * kS;
  const size_t yrow = (size_t)eb * kS * kH + jc;

#pragma unroll 1
  for (int s = 0; s < kS; ++s) {
    const unsigned short* hb = hbuf + (s & 1) * (kB * kH);
    const unsigned short* cb = cbuf + (s & 1) * (kB * kH);
    unsigned short* hbn = hbuf + ((s + 1) & 1) * (kB * kH);
    unsigned short* cbn = cbuf + ((s + 1) & 1) * (kB * kH);
    const unsigned short* xs = Xb + (size_t)s * kH;

    f32x4 a0 = {0.f, 0.f, 0.f, 0.f}, a1 = a0, ad = a0;
#pragma unroll 4
    for (int kk = 0; kk < 24; ++kk) {
      const int o = kk * 32;
      short8 hf0 = *(const short8*)(hb + hoff[0] + o);
      a0 = __builtin_amdgcn_mfma_f32_16x16x32_bf16(hf0, wg[kk], a0, 0, 0, 0);
      short8 xf0 = *(const short8*)(xs + xoff[0] + o);
      a0 = __builtin_amdgcn_mfma_f32_16x16x32_bf16(xf0, ug[kk], a0, 0, 0, 0);
      short8 hf1 = *(const short8*)(hb + hoff[1] + o);
      a1 = __builtin_amdgcn_mfma_f32_16x16x32_bf16(hf1, wg[kk], a1, 0, 0, 0);
      short8 xf1 = *(const short8*)(xs + xoff[1] + o);
      a1 = __builtin_amdgcn_mfma_f32_16x16x32_bf16(xf1, ug[kk], a1, 0, 0, 0);
      if (do_c) {
        short8 cf = *(const short8*)(cb + coff + o);
        ad = __builtin_amdgcn_mfma_f32_16x16x32_bf16(cf, wdv[kk], ad, 0, 0, 0);
      }
    }
    // C/D layout: row = lhi*4+r, col = l15
#pragma unroll
    for (int r = 0; r < 4; ++r) {
      lds_pre[w][0 + lhi * 4 + r][l15] = a0[r];
      lds_pre[w][16 + lhi * 4 + r][l15] = a1[r];
    }
    if (do_c) {
#pragma unroll
      for (int r = 0; r < 4; ++r) lds_d[w * 16 + lhi * 4 + r][l15] = ad[r];
    }
    __syncthreads();

    const float tv = tsrow[s];
    float hn[2], cn[2];
#pragma unroll
    for (int u = 0; u < 2; ++u) {
      const int jj = eq * 2 + u;
      float cs1 = ftanh(lds_d[erow][jj] + bd[u]);
      float cold = lds_cm[erow][jj];
      float cadj = cold + cs1 * (tv - 1.0f);  // (c - cs1) + cs1*t
      float fv = fsigm(lds_pre[0][erow][jj] + bsum[0][u]);
      float iv = fsigm(lds_pre[1][erow][jj] + bsum[1][u]);
      float ov = fsigm(lds_pre[2][erow][jj] + bsum[2][u]);
      float cv = fsigm(lds_pre[3][erow][jj] + bsum[3][u]);
      float cnew = fv * cadj + iv * cv;
      float hnew = ov * ftanh(cnew);
      lds_cm[erow][jj] = cnew;
      hn[u] = hnew;
      cn[u] = cnew;
    }
    *(float2*)(ys + yrow + (size_t)s * kH) = make_float2(hn[0], hn[1]);
    *(ushort2*)(hbn + eb * kH + jc) = make_ushort2(f2bf(hn[0]), f2bf(hn[1]));
    *(ushort2*)(cbn + eb * kH + jc) = make_ushort2(f2bf(cn[0]), f2bf(cn[1]));

    if (s != kS - 1) group_barrier(cnt, 48u * (unsigned)(s + 1));
  }
}

extern "C" void kernel_launch(void* const* d_in, const int* in_sizes, int n_in,
                              void* d_out, int out_size, void* d_ws, size_t ws_size,
                              hipStream_t stream) {
  const float* inputs = (const float*)d_in[0];
  const float* tsp    = (const float*)d_in[1];
  const float* h0     = (const float*)d_in[2];
  const float* c0     = (const float*)d_in[3];
  const float* Wall   = (const float*)d_in[4];
  const float* Wallb  = (const float*)d_in[5];
  const float* Uall   = (const float*)d_in[6];
  const float* Uallb  = (const float*)d_in[7];
  const float* Wd     = (const float*)d_in[8];
  const float* Wdb    = (const float*)d_in[9];
  float* ys = (float*)d_out;

  char* ws = (char*)d_ws;
  unsigned* bar        = (unsigned*)(ws);                 // 1 KB (4 counters, 64B apart)
  unsigned short* hbuf = (unsigned short*)(ws + 1024);    // 393,216 B (ping-pong)
  unsigned short* cbuf = (unsigned short*)(ws + 394240);  // 393,216 B (ping-pong)
  unsigned short* Xb   = (unsigned short*)(ws + 787456);  // 100,663,296 B

  hipMemsetAsync(bar, 0, 1024, stream);
  cast_bf16_kernel<<<49152, 256, 0, stream>>>(inputs, Xb, kB * kS * kH);
  cast_bf16_kernel<<<96, 256, 0, stream>>>(h0, hbuf, kB * kH);
  cast_bf16_kernel<<<96, 256, 0, stream>>>(c0, cbuf, kB * kH);
  fill_kernel<<<49152, 256, 0, stream>>>(ys, kB * kS * kH);  // canary; scan overwrites all

  scan_kernel<<<192, 256, 0, stream>>>(Xb, hbuf, cbuf, Wall, Wallb, Uall, Uallb,
                                       Wd, Wdb, tsp, c0, ys, bar);
}